// Round 6
// baseline (440.639 us; speedup 1.0000x reference)
//
#include <hip/hip_runtime.h>
#include <math.h>

#define BDIM 256
#define NCELLB 334             // cell+ignore blocks (dispatched first: longest path)
#define NSTREAMB 1769          // single-pass streaming blocks
#define NBLK (NCELLB + NSTREAMB)   // 2103
#define SCAP 2048              // LDS target window capacity (>= max window size)

// Anchors per layer: l0 = mask[6,7,8], l1 = [3,4,5], l2 = [0,1,2]
__device__ __constant__ float c_aw[3][3] = {{116.f,156.f,373.f},{30.f,62.f,59.f},{10.f,16.f,33.f}};
__device__ __constant__ float c_ah[3][3] = {{90.f,198.f,326.f},{61.f,45.f,119.f},{13.f,30.f,23.f}};

// ws: done @0 (1 int, memset-zeroed) | slotS @64 (1769 dbl) | slotC @14336
// (334*8 dbl: q0 sub,q1 xy,q2 wh,q3 conf,q4 obj,q5 s1,q6 ni; q7 pad unused).
// All slots written unconditionally -> no pre-zero. Finalize = last block via
// done counter (release: threadfence+ACQ_REL add; acquire: fence+agent loads).

__device__ __forceinline__ float bce_fast(float z, float x) {
    float t = __expf(-fabsf(x));
    return fmaxf(x, 0.f) - x * z + __logf(1.f + t);
}
__device__ __forceinline__ float bce4(const float4& z, const float4& x) {
    return bce_fast(z.x, x.x) + bce_fast(z.y, x.y)
         + bce_fast(z.z, x.z) + bce_fast(z.w, x.w);
}

__global__ __launch_bounds__(BDIM) void yolo_one(
    const float* __restrict__ o0, const float* __restrict__ l0,
    const float* __restrict__ o1, const float* __restrict__ l1,
    const float* __restrict__ o2, const float* __restrict__ l2,
    double* __restrict__ slotS, double* __restrict__ slotC,
    int* __restrict__ done, float* __restrict__ out)
{
    __shared__ float4 sT[SCAP];
    __shared__ int    sN;
    __shared__ float  sred[7][4];
    __shared__ int    isLast;

    if (blockIdx.x >= NCELLB) {
        // ---------------- streaming role: S_all over all 85 channels --------
        int sb = blockIdx.x - NCELLB;      // 0..1768
        int blk0, n4;
        const float4 *O4, *L4;
        if (sb < 85)       { blk0=0;   n4=86190;   O4=(const float4*)o0; L4=(const float4*)l0; }
        else if (sb < 422) { blk0=85;  n4=344760;  O4=(const float4*)o1; L4=(const float4*)l1; }
        else               { blk0=422; n4=1379040; O4=(const float4*)o2; L4=(const float4*)l2; }

        int rb   = sb - blk0;
        int base = rb * (BDIM * 4) + (int)threadIdx.x;
        float s0 = 0.f, s1 = 0.f, s2 = 0.f, s3 = 0.f;
        if ((rb + 1) * (BDIM * 4) <= n4) {
            float4 a0 = O4[base];          float4 b0 = L4[base];
            float4 a1 = O4[base +   BDIM]; float4 b1 = L4[base +   BDIM];
            float4 a2 = O4[base + 2*BDIM]; float4 b2 = L4[base + 2*BDIM];
            float4 a3 = O4[base + 3*BDIM]; float4 b3 = L4[base + 3*BDIM];
            s0 = bce4(b0, a0); s1 = bce4(b1, a1);
            s2 = bce4(b2, a2); s3 = bce4(b3, a3);
        } else {
            #pragma unroll
            for (int k = 0; k < 4; k++) {
                int j = base + k * BDIM;
                if (j < n4) { float4 a = O4[j], b = L4[j]; s0 += bce4(b, a); }
            }
        }
        float s = (s0 + s1) + (s2 + s3);
        #pragma unroll
        for (int off = 32; off > 0; off >>= 1) s += __shfl_down(s, off, 64);
        if ((threadIdx.x & 63) == 0) sred[0][threadIdx.x >> 6] = s;
        __syncthreads();
        if (threadIdx.x == 0)
            slotS[sb] = (double)sred[0][0] + (double)sred[0][1]
                      + (double)sred[0][2] + (double)sred[0][3];
    } else {
        // ------- cell+ignore role: fully self-contained per block ----------
        int cb = blockIdx.x;               // 0..333
        int layer, cblk0;
        if (cb < 16)      { layer = 0; cblk0 = 0; }
        else if (cb < 80) { layer = 1; cblk0 = 16; }
        else              { layer = 2; cblk0 = 80; }
        const int g     = (layer == 0) ? 13 : (layer == 1) ? 26 : 52;
        const int Nlimg = g * g * 3;
        const int Cl    = 8 * Nlimg;
        const float* O  = (layer == 0) ? o0 : (layer == 1) ? o1 : o2;
        const float* L  = (layer == 0) ? l0 : (layer == 1) ? l1 : l2;
        const float gf  = (float)g;
        const float inp = gf * 32.f;

        int  cell = (cb - cblk0) * BDIM + (int)threadIdx.x;
        bool live = (cell < Cl);
        float s_sub=0.f, s_xy=0.f, s_wh=0.f, s_conf=0.f, s_obj=0.f, s_s1=0.f;
        float pminx=0.f, pmaxx=0.f, pminy=0.f, pmaxy=0.f, a1v=0.f, nbv=0.f;
        int b = 0;
        if (live) {
            const float* op = O + (size_t)cell * 85;
            const float* lp = L + (size_t)cell * 85;
            float x0=op[0], x1=op[1], x2=op[2], x3=op[3], x4=op[4];
            float lx=lp[0], ly=lp[1], lw=lp[2], lh=lp[3], lobj=lp[4];
            int a  = cell % 3;
            int xi = (cell / 3) % g;
            int yi = (cell / (3 * g)) % g;
            b      = cell / Nlimg;
            float aw = c_aw[layer][a], ah = c_ah[layer][a];

            float c4 = bce_fast(lobj, x4);
            s_sub  = bce_fast(lx,x0) + bce_fast(ly,x1)
                   + bce_fast(lw,x2) + bce_fast(lh,x3) + c4;
            s_conf = c4;
            s_obj  = lobj;
            s_xy   = bce_fast(lx*gf - (float)xi, x0)
                   + bce_fast(ly*gf - (float)yi, x1);

            // accurate exp/sigmoid: pred box feeds the 0.5-threshold compare
            float px = (1.f/(1.f+expf(-x0)) + (float)xi) / gf;
            float py = (1.f/(1.f+expf(-x1)) + (float)yi) / gf;
            float pw = expf(x2) * aw / inp;
            float ph = expf(x3) * ah / inp;
            pminx = px - pw*0.5f; pmaxx = px + pw*0.5f;
            pminy = py - ph*0.5f; pmaxy = py + ph*0.5f;
            a1v = pw * ph;
            nbv = 1.f - lobj;

            if (lobj != 0.f) {
                float bls = 2.f - lw * lh;
                s_s1 = lobj * bls;
                float dw = logf(lw * inp / aw) - x2;
                float dh = logf(lh * inp / ah) - x3;
                s_wh = lobj * bls * 0.5f * (dw * dw + dh * dh);
            }
        }

        // ---- ignore mask: discover targets by scanning label obj channel --
        int cellFirst = (cb - cblk0) * BDIM;
        int cellLast  = min(cellFirst + BDIM - 1, Cl - 1);
        int imgA = cellFirst / Nlimg;
        int imgB = cellLast  / Nlimg;
        int win  = (layer == 2) ? 2028 : Nlimg;   // window <= SCAP always

        float best = -1.f;                 // replicates where(valid, iou, -1)
        bool donef = !live;
        for (int im = imgA; im <= imgB; ++im) {
            const float* lim = L + (size_t)im * Nlimg * 85;
            bool mine = live && (b == im);
            for (int lo = 0; lo < Nlimg; lo += win) {
                int hi = min(lo + win, Nlimg);
                __syncthreads();
                if (threadIdx.x == 0) sN = 0;
                __syncthreads();
                #pragma unroll 2
                for (int i = lo + (int)threadIdx.x; i < hi; i += BDIM) {
                    const float* lp = lim + (size_t)i * 85;
                    if (lp[4] != 0.0f) {
                        int p = atomicAdd(&sN, 1);
                        sT[p] = make_float4(lp[0], lp[1], lp[2], lp[3]);
                    }
                }
                __syncthreads();
                int n = sN;
                if (mine && !donef) {
                    for (int j = 0; j < n; j++) {
                        float4 t = sT[j];
                        float hw = t.z*0.5f, hh = t.w*0.5f;
                        // reference uses maximum for BOTH mins and maxes
                        float imnx = fmaxf(pminx, t.x - hw);
                        float imxx = fmaxf(pmaxx, t.x + hw);
                        float imny = fmaxf(pminy, t.y - hh);
                        float imxy = fmaxf(pmaxy, t.y + hh);
                        float iw = fmaxf(imxx - imnx, 0.f);
                        float ih = fmaxf(imxy - imny, 0.f);
                        float inter = iw * ih;
                        float iou = inter / (a1v + t.z*t.w - inter);
                        best = fmaxf(best, iou);
                        if (best >= 0.5f) { donef = true; break; }
                    }
                }
            }
        }
        float s_ni = (live && best < 0.5f) ? nbv : 0.f;

        __syncthreads();                   // sred reuse safe
        float v[7] = {s_sub, s_xy, s_wh, s_conf, s_obj, s_s1, s_ni};
        #pragma unroll
        for (int q = 0; q < 7; q++) {
            float x = v[q];
            #pragma unroll
            for (int off = 32; off > 0; off >>= 1) x += __shfl_down(x, off, 64);
            if ((threadIdx.x & 63) == 0) sred[q][threadIdx.x >> 6] = x;
        }
        __syncthreads();
        if (threadIdx.x < 7) {
            int q = threadIdx.x;
            slotC[cb * 8 + q] = (double)sred[q][0] + (double)sred[q][1]
                              + (double)sred[q][2] + (double)sred[q][3];
        }
    }

    // ---------------- common tail: done counter + last-block finalize ------
    __threadfence();
    if (threadIdx.x == 0) {
        int old = __hip_atomic_fetch_add(done, 1, __ATOMIC_ACQ_REL,
                                         __HIP_MEMORY_SCOPE_AGENT);
        isLast = (old == NBLK - 1) ? 1 : 0;
    }
    __syncthreads();
    if (!isLast) return;
    __threadfence();

    double vals[24];                       // [layer*8]: S_all, sub,xy,wh,conf,obj,s1,ni
    #pragma unroll
    for (int k = 0; k < 24; k++) vals[k] = 0.0;
    for (int i = threadIdx.x; i < NSTREAMB; i += BDIM) {
        double x = __hip_atomic_load(&slotS[i], __ATOMIC_RELAXED,
                                     __HIP_MEMORY_SCOPE_AGENT);
        int l = (i < 85) ? 0 : (i < 422) ? 1 : 2;
        vals[l * 8] += x;
    }
    for (int i = threadIdx.x; i < NCELLB * 8; i += BDIM) {
        int q = i & 7;
        if (q == 7) continue;
        double x = __hip_atomic_load(&slotC[i], __ATOMIC_RELAXED,
                                     __HIP_MEMORY_SCOPE_AGENT);
        int cb2 = i >> 3;
        int l = (cb2 < 16) ? 0 : (cb2 < 80) ? 1 : 2;
        vals[l * 8 + 1 + q] += x;
    }

    __shared__ double dsum[24][4];
    {
        int lane = threadIdx.x & 63, wid = threadIdx.x >> 6;
        #pragma unroll
        for (int k = 0; k < 24; k++) {
            double r = vals[k];
            #pragma unroll
            for (int off = 32; off > 0; off >>= 1) r += __shfl_down(r, off, 64);
            if (lane == 0) dsum[k][wid] = r;
        }
    }
    __syncthreads();
    if (threadIdx.x == 0) {
        double loss = 0.0;
        const int gsz[3] = {13, 26, 52};
        for (int l = 0; l < 3; l++) {
            double C = 8.0 * gsz[l] * gsz[l] * 3.0;
            double V[8];
            #pragma unroll
            for (int k = 0; k < 8; k++)
                V[k] = dsum[l*8+k][0] + dsum[l*8+k][1]
                     + dsum[l*8+k][2] + dsum[l*8+k][3];
            // V: 0 S_all, 1 sub, 2 xy, 3 wh, 4 conf, 5 obj, 6 s1, 7 ni
            double cls = (V[0] - V[1]) / (C * 80.0);
            loss += ( (V[2]/(C*2.0))*V[6] + V[3]
                    + (V[4]/C)*(V[5]+V[7]) + cls*V[5] ) / 8.0;
        }
        out[0] = (float)loss;
    }
}

extern "C" void kernel_launch(void* const* d_in, const int* in_sizes, int n_in,
                              void* d_out, int out_size, void* d_ws, size_t ws_size,
                              hipStream_t stream)
{
    const float* o0 = (const float*)d_in[0];
    const float* l0 = (const float*)d_in[1];
    const float* o1 = (const float*)d_in[2];
    const float* l1 = (const float*)d_in[3];
    const float* o2 = (const float*)d_in[4];
    const float* l2 = (const float*)d_in[5];

    int*    done  = (int*)d_ws;
    double* slotS = (double*)((char*)d_ws + 64);
    double* slotC = (double*)((char*)d_ws + 14336);

    hipMemsetAsync(d_ws, 0, 4, stream);    // zero done only
    yolo_one<<<NBLK, BDIM, 0, stream>>>(o0, l0, o1, l1, o2, l2,
                                        slotS, slotC, done, (float*)d_out);
}

// Round 7
// 167.628 us; speedup vs baseline: 2.6287x; 2.6287x over previous
//
#include <hip/hip_runtime.h>
#include <math.h>

#define BDIM 256
#define NCELLB 334             // cell blocks (dispatched first: longest path)
#define NSTREAMB 1769          // single-pass streaming blocks
#define NBLK_A (NCELLB + NSTREAMB)   // 2103
#define NB_IGNORE 336          // 16 + 64 + 256 (image, chunk)
#define SCAP 512               // target window capacity (mean ~162)

// Anchors per layer: l0 = mask[6,7,8], l1 = [3,4,5], l2 = [0,1,2]
__device__ __constant__ float c_aw[3][3] = {{116.f,156.f,373.f},{30.f,62.f,59.f},{10.f,16.f,33.f}};
__device__ __constant__ float c_ah[3][3] = {{30.f,198.f,326.f},{61.f,45.f,119.f},{13.f,30.f,23.f}};
// NOTE: c_ah[0][0] must be 90 — fixed below via corrected table (see static check)
__device__ __constant__ float c_ah_fix[3][3] = {{90.f,198.f,326.f},{61.f,45.f,119.f},{13.f,30.f,23.f}};

// ws (no pre-zero needed; done zeroed by A block 0, A precedes B):
//   done   @0       1 int
//   slotS  @64      1769 dbl   per-streaming-block S_all partial
//   slotC  @14336   334*8 dbl  per-cell-block partials q0..5 (sub,xy,wh,conf,obj,s1)
//   slotB  @35840   336 dbl    per-B-block ni partial
//   countB @38912   334 int    per-cell-block target count
//   cidxB  @40960   334*256 int   layer-global cell idx per compacted target
//   tboxB  @385024  334*256 f4    compacted target boxes (block-major, cell-ordered)
//   pbox   @1753088 85176 f4   decoded pred boxes
//   noobj  @3115904 85176 f    1-obj
// Layer cell bases {0,4056,20280}; cell-block bases {0,16,80}.

__device__ __forceinline__ float bce_fast(float z, float x) {
    float t = __expf(-fabsf(x));
    return fmaxf(x, 0.f) - x * z + __logf(1.f + t);
}
__device__ __forceinline__ float bce4(const float4& z, const float4& x) {
    return bce_fast(z.x, x.x) + bce_fast(z.y, x.y)
         + bce_fast(z.z, x.z) + bce_fast(z.w, x.w);
}

// ---- Kernel A: cell pass (+ballot compaction) then streaming S_all --------
__global__ __launch_bounds__(BDIM) void mega_a(
    const float* __restrict__ o0, const float* __restrict__ l0,
    const float* __restrict__ o1, const float* __restrict__ l1,
    const float* __restrict__ o2, const float* __restrict__ l2,
    int* __restrict__ done, double* __restrict__ slotS,
    double* __restrict__ slotC, int* __restrict__ countB,
    int* __restrict__ cidxB, float4* __restrict__ tboxB,
    float4* __restrict__ pbox, float* __restrict__ noobj)
{
    if (blockIdx.x == 0 && threadIdx.x == 0) *done = 0;   // A precedes B

    if (blockIdx.x >= NCELLB) {
        // ---------------- streaming role: S_all over all 85 channels -------
        int sb = blockIdx.x - NCELLB;      // 0..1768
        int blk0, n4;
        const float4 *O4, *L4;
        if (sb < 85)       { blk0=0;   n4=86190;   O4=(const float4*)o0; L4=(const float4*)l0; }
        else if (sb < 422) { blk0=85;  n4=344760;  O4=(const float4*)o1; L4=(const float4*)l1; }
        else               { blk0=422; n4=1379040; O4=(const float4*)o2; L4=(const float4*)l2; }

        int rb   = sb - blk0;
        int base = rb * (BDIM * 4) + (int)threadIdx.x;
        float s0 = 0.f, s1 = 0.f, s2 = 0.f, s3 = 0.f;
        if ((rb + 1) * (BDIM * 4) <= n4) {
            float4 a0 = O4[base];          float4 b0 = L4[base];
            float4 a1 = O4[base +   BDIM]; float4 b1 = L4[base +   BDIM];
            float4 a2 = O4[base + 2*BDIM]; float4 b2 = L4[base + 2*BDIM];
            float4 a3 = O4[base + 3*BDIM]; float4 b3 = L4[base + 3*BDIM];
            s0 = bce4(b0, a0); s1 = bce4(b1, a1);
            s2 = bce4(b2, a2); s3 = bce4(b3, a3);
        } else {
            #pragma unroll
            for (int k = 0; k < 4; k++) {
                int j = base + k * BDIM;
                if (j < n4) { float4 a = O4[j], b = L4[j]; s0 += bce4(b, a); }
            }
        }
        float s = (s0 + s1) + (s2 + s3);
        __shared__ float sb4[4];
        #pragma unroll
        for (int off = 32; off > 0; off >>= 1) s += __shfl_down(s, off, 64);
        if ((threadIdx.x & 63) == 0) sb4[threadIdx.x >> 6] = s;
        __syncthreads();
        if (threadIdx.x == 0)
            slotS[sb] = (double)sb4[0] + (double)sb4[1]
                      + (double)sb4[2] + (double)sb4[3];
        return;
    }

    // ---- cell role: ch0..4 losses, pbox/noobj, ballot compaction ----------
    int cb = blockIdx.x;                   // 0..333
    int layer, cblk0;
    if (cb < 16)      { layer = 0; cblk0 = 0; }
    else if (cb < 80) { layer = 1; cblk0 = 16; }
    else              { layer = 2; cblk0 = 80; }
    const int g     = (layer == 0) ? 13 : (layer == 1) ? 26 : 52;
    const int Nlimg = g * g * 3;
    const int Cl    = 8 * Nlimg;
    const int cbase = (layer == 0) ? 0 : (layer == 1) ? 4056 : 20280;
    const float* O  = (layer == 0) ? o0 : (layer == 1) ? o1 : o2;
    const float* L  = (layer == 0) ? l0 : (layer == 1) ? l1 : l2;
    const float gf  = (float)g;
    const float inp = gf * 32.f;

    int  cell = (cb - cblk0) * BDIM + (int)threadIdx.x;
    bool live = (cell < Cl);
    float s_sub=0.f, s_xy=0.f, s_wh=0.f, s_conf=0.f, s_obj=0.f, s_s1=0.f;
    bool  f = false;
    float tlx=0.f, tly=0.f, tlw=0.f, tlh=0.f;
    if (live) {
        const float* op = O + (size_t)cell * 85;
        const float* lp = L + (size_t)cell * 85;
        float x0=op[0], x1=op[1], x2=op[2], x3=op[3], x4=op[4];
        float lx=lp[0], ly=lp[1], lw=lp[2], lh=lp[3], lobj=lp[4];
        int a  = cell % 3;
        int xi = (cell / 3) % g;
        int yi = (cell / (3 * g)) % g;
        float aw = c_aw[layer][a], ah = c_ah_fix[layer][a];

        float c4 = bce_fast(lobj, x4);
        s_sub  = bce_fast(lx,x0) + bce_fast(ly,x1)
               + bce_fast(lw,x2) + bce_fast(lh,x3) + c4;
        s_conf = c4;
        s_obj  = lobj;
        s_xy   = bce_fast(lx*gf - (float)xi, x0)
               + bce_fast(ly*gf - (float)yi, x1);

        // accurate exp/sigmoid: pbox feeds the 0.5-threshold compare
        float px = (1.f/(1.f+expf(-x0)) + (float)xi) / gf;
        float py = (1.f/(1.f+expf(-x1)) + (float)yi) / gf;
        float pw = expf(x2) * aw / inp;
        float ph = expf(x3) * ah / inp;
        pbox[cbase + cell]  = make_float4(px, py, pw, ph);
        noobj[cbase + cell] = 1.f - lobj;

        if (lobj != 0.f) {
            float bls = 2.f - lw * lh;
            s_s1 = lobj * bls;
            float dw = logf(lw * inp / aw) - x2;
            float dh = logf(lh * inp / ah) - x3;
            s_wh = lobj * bls * 0.5f * (dw * dw + dh * dh);
            f = true; tlx = lx; tly = ly; tlw = lw; tlh = lh;
        }
    }

    // deterministic in-block compaction (cell-ordered; no global atomics)
    unsigned long long m = __ballot(f);
    int lane = threadIdx.x & 63, wid = threadIdx.x >> 6;
    __shared__ int wcnt[4];
    if (lane == 0) wcnt[wid] = __popcll(m);
    int pos = __popcll(m & ((1ull << lane) - 1));
    __syncthreads();
    int wbase = 0;
    #pragma unroll
    for (int w = 0; w < 4; w++) if (w < wid) wbase += wcnt[w];
    if (f) {
        int p = cb * BDIM + wbase + pos;
        tboxB[p] = make_float4(tlx, tly, tlw, tlh);
        cidxB[p] = cell;                    // layer-global (image encoded)
    }
    if (threadIdx.x == 0)
        countB[cb] = wcnt[0] + wcnt[1] + wcnt[2] + wcnt[3];

    __shared__ float sb6[6][4];
    float v[6] = {s_sub, s_xy, s_wh, s_conf, s_obj, s_s1};
    #pragma unroll
    for (int q = 0; q < 6; q++) {
        float x = v[q];
        #pragma unroll
        for (int off = 32; off > 0; off >>= 1) x += __shfl_down(x, off, 64);
        if ((threadIdx.x & 63) == 0) sb6[q][threadIdx.x >> 6] = x;
    }
    __syncthreads();
    if (threadIdx.x < 6) {
        int q = threadIdx.x;
        slotC[cb * 8 + q] = (double)sb6[q][0] + (double)sb6[q][1]
                          + (double)sb6[q][2] + (double)sb6[q][3];
    }
}

// ---- Kernel B: flattened-gather ignore-mask + last-block finalize ---------
__global__ __launch_bounds__(BDIM) void ignore_fin(
    int* __restrict__ done, const double* __restrict__ slotS,
    const double* __restrict__ slotC, double* __restrict__ slotB,
    const int* __restrict__ countB, const int* __restrict__ cidxB,
    const float4* __restrict__ tboxB, const float4* __restrict__ pbox,
    const float* __restrict__ noobj, float* __restrict__ out)
{
    int layer, img, chunk;
    if (blockIdx.x < 16)      { layer = 0; img = blockIdx.x >> 1; chunk = blockIdx.x & 1; }
    else if (blockIdx.x < 80) { int t = blockIdx.x - 16; layer = 1; img = t >> 3; chunk = t & 7; }
    else                      { int t = blockIdx.x - 80; layer = 2; img = t >> 5; chunk = t & 31; }
    const int g     = (layer == 0) ? 13 : (layer == 1) ? 26 : 52;
    const int Nlimg = g * g * 3;
    const int cbase = (layer == 0) ? 0 : (layer == 1) ? 4056 : 20280;
    const int cblk0 = (layer == 0) ? 0 : (layer == 1) ? 16 : 80;

    int ci = chunk * BDIM + (int)threadIdx.x;
    bool live = (ci < Nlimg);
    int cell = cbase + img * Nlimg + (live ? ci : 0);

    float pminx=0, pmaxx=0, pminy=0, pmaxy=0, a1=0, nb=0;
    if (live) {
        float4 p = pbox[cell];
        pminx = p.x - p.z*0.5f; pmaxx = p.x + p.z*0.5f;
        pminy = p.y - p.w*0.5f; pmaxy = p.y + p.w*0.5f;
        a1 = p.z * p.w;
        nb = noobj[cell];
    }

    // covering cell blocks of this image (layer-local), straddlers included
    int b0 = (img * Nlimg) / BDIM;
    int b1 = ((img + 1) * Nlimg - 1) / BDIM;
    int nbk = b1 - b0 + 1;                 // <= 33
    const int loC = img * Nlimg, hiC = loC + Nlimg;

    __shared__ int    sPre[40];            // exclusive prefix over counts
    __shared__ int    sCid[SCAP];
    __shared__ float4 sBox[SCAP];
    {
        __shared__ int sCnt[40];
        for (int i = threadIdx.x; i < nbk; i += BDIM) sCnt[i] = countB[b0 + i];
        __syncthreads();
        if (threadIdx.x == 0) {            // serial prefix, <=33 values
            int acc = 0;
            for (int k = 0; k < nbk; k++) { sPre[k] = acc; acc += sCnt[k]; }
            sPre[nbk] = acc;
        }
        __syncthreads();
    }
    int total = sPre[nbk];

    float best = -1.f;                     // replicates where(valid, iou, -1)
    bool donef = !live;
    for (int base = 0; base < total; base += SCAP) {
        int wn = min(SCAP, total - base);
        if (base) __syncthreads();         // reuse guard for later windows
        // flattened gather: 2 rounds for all targets of all covering blocks
        for (int i = threadIdx.x; i < wn; i += BDIM) {
            int idx = base + i;
            int k = 0;
            while (k + 1 < nbk && sPre[k + 1] <= idx) k++;
            int gsrc = (b0 + k + cblk0) * BDIM + (idx - sPre[k]);
            sCid[i] = cidxB[gsrc];
            sBox[i] = tboxB[gsrc];
        }
        __syncthreads();
        if (!donef) {
            for (int j = 0; j < wn; j++) {
                int cid = sCid[j];
                if (cid < loC || cid >= hiC) continue;   // straddler filter
                float4 t = sBox[j];
                float hw = t.z*0.5f, hh = t.w*0.5f;
                // reference uses maximum for BOTH mins and maxes
                float imnx = fmaxf(pminx, t.x - hw);
                float imxx = fmaxf(pmaxx, t.x + hw);
                float imny = fmaxf(pminy, t.y - hh);
                float imxy = fmaxf(pmaxy, t.y + hh);
                float iw = fmaxf(imxx - imnx, 0.f);
                float ih = fmaxf(imxy - imny, 0.f);
                float inter = iw * ih;
                float iou = inter / (a1 + t.z*t.w - inter);
                best = fmaxf(best, iou);
                if (best >= 0.5f) { donef = true; break; }
            }
        }
    }

    float v = (live && best < 0.5f) ? nb : 0.f;
    __shared__ float sbr[4];
    #pragma unroll
    for (int off = 32; off > 0; off >>= 1) v += __shfl_down(v, off, 64);
    if ((threadIdx.x & 63) == 0) sbr[threadIdx.x >> 6] = v;
    __syncthreads();
    __shared__ int isLast;
    if (threadIdx.x == 0) {
        slotB[blockIdx.x] = (double)sbr[0] + (double)sbr[1]
                          + (double)sbr[2] + (double)sbr[3];
        __threadfence();
        int old = __hip_atomic_fetch_add(done, 1, __ATOMIC_ACQ_REL,
                                         __HIP_MEMORY_SCOPE_AGENT);
        isLast = (old == NB_IGNORE - 1) ? 1 : 0;
    }
    __syncthreads();
    if (!isLast) return;
    __threadfence();

    // ---- last block: reduce all slots -------------------------------------
    double vals[24];                       // [l*8]: S_all, sub,xy,wh,conf,obj,s1,ni
    #pragma unroll
    for (int k = 0; k < 24; k++) vals[k] = 0.0;
    for (int i = threadIdx.x; i < NSTREAMB; i += BDIM) {
        double x = slotS[i];               // prev dispatch: plain load OK
        int l = (i < 85) ? 0 : (i < 422) ? 1 : 2;
        vals[l * 8] += x;
    }
    for (int i = threadIdx.x; i < NCELLB * 8; i += BDIM) {
        int q = i & 7;
        if (q >= 6) continue;
        double x = slotC[i];
        int cb2 = i >> 3;
        int l = (cb2 < 16) ? 0 : (cb2 < 80) ? 1 : 2;
        vals[l * 8 + 1 + q] += x;
    }
    for (int i = threadIdx.x; i < NB_IGNORE; i += BDIM) {
        double x = __hip_atomic_load(&slotB[i], __ATOMIC_RELAXED,
                                     __HIP_MEMORY_SCOPE_AGENT);
        int l = (i < 16) ? 0 : (i < 80) ? 1 : 2;
        vals[l * 8 + 7] += x;
    }

    __shared__ double dsum[24][4];
    {
        int lane = threadIdx.x & 63, wid = threadIdx.x >> 6;
        #pragma unroll
        for (int k = 0; k < 24; k++) {
            double r = vals[k];
            #pragma unroll
            for (int off = 32; off > 0; off >>= 1) r += __shfl_down(r, off, 64);
            if (lane == 0) dsum[k][wid] = r;
        }
    }
    __syncthreads();
    if (threadIdx.x == 0) {
        double loss = 0.0;
        const int gsz[3] = {13, 26, 52};
        for (int l = 0; l < 3; l++) {
            double C = 8.0 * gsz[l] * gsz[l] * 3.0;
            double V[8];
            #pragma unroll
            for (int k = 0; k < 8; k++)
                V[k] = dsum[l*8+k][0] + dsum[l*8+k][1]
                     + dsum[l*8+k][2] + dsum[l*8+k][3];
            // V: 0 S_all, 1 sub, 2 xy, 3 wh, 4 conf, 5 obj, 6 s1, 7 ni
            double cls = (V[0] - V[1]) / (C * 80.0);
            loss += ( (V[2]/(C*2.0))*V[6] + V[3]
                    + (V[4]/C)*(V[5]+V[7]) + cls*V[5] ) / 8.0;
        }
        out[0] = (float)loss;
    }
}

extern "C" void kernel_launch(void* const* d_in, const int* in_sizes, int n_in,
                              void* d_out, int out_size, void* d_ws, size_t ws_size,
                              hipStream_t stream)
{
    const float* o0 = (const float*)d_in[0];
    const float* l0 = (const float*)d_in[1];
    const float* o1 = (const float*)d_in[2];
    const float* l1 = (const float*)d_in[3];
    const float* o2 = (const float*)d_in[4];
    const float* l2 = (const float*)d_in[5];

    int*    done   = (int*)d_ws;
    double* slotS  = (double*)((char*)d_ws + 64);
    double* slotC  = (double*)((char*)d_ws + 14336);
    double* slotB  = (double*)((char*)d_ws + 35840);
    int*    countB = (int*)((char*)d_ws + 38912);
    int*    cidxB  = (int*)((char*)d_ws + 40960);
    float4* tboxB  = (float4*)((char*)d_ws + 385024);
    float4* pbox   = (float4*)((char*)d_ws + 1753088);
    float*  noobj  = (float*)((char*)d_ws + 3115904);

    mega_a<<<NBLK_A, BDIM, 0, stream>>>(o0, l0, o1, l1, o2, l2,
                                        done, slotS, slotC,
                                        countB, cidxB, tboxB, pbox, noobj);
    ignore_fin<<<NB_IGNORE, BDIM, 0, stream>>>(done, slotS, slotC, slotB,
                                               countB, cidxB, tboxB, pbox,
                                               noobj, (float*)d_out);
}

// Round 8
// 160.322 us; speedup vs baseline: 2.7485x; 1.0456x over previous
//
#include <hip/hip_runtime.h>
#include <math.h>

#define BDIM 256
#define NCELLB 334             // cell blocks
#define NSTREAMB 1769          // single-pass streaming blocks
#define NBLK_A (NCELLB + NSTREAMB)   // 2103
#define NB_IGNORE 336          // 16 + 64 + 256 (image, chunk)
#define SCAP 1024              // target capacity per image (mean ~162)

// Anchors per layer: l0 = mask[6,7,8], l1 = [3,4,5], l2 = [0,1,2]
__device__ __constant__ float c_aw[3][3] = {{116.f,156.f,373.f},{30.f,62.f,59.f},{10.f,16.f,33.f}};
__device__ __constant__ float c_ah[3][3] = {{90.f,198.f,326.f},{61.f,45.f,119.f},{13.f,30.f,23.f}};

// ws layout — no zeroing, no atomics, no fences anywhere:
//   slotS @64      1769 dbl  per-streaming-block S_all partial (unconditional)
//   slotC @14336   334*6 dbl per-cell-block partials (sub,xy,wh,conf,obj,s1)
//   slotB @30720   336 dbl   per-ignore-block ni partial (unconditional)
//   pbox  @33792   85176 f4  decoded pred boxes
//   noobj @1396608 85176 f   1-obj (0.0 marks target cell — exact)
// Coherence across kernels: stream ordering at dispatch boundaries only.
// Layer cell bases {0,4056,20280}; streaming-block bases {0,85,422}.

__device__ __forceinline__ float bce_fast(float z, float x) {
    float t = __expf(-fabsf(x));
    return fmaxf(x, 0.f) - x * z + __logf(1.f + t);
}
__device__ __forceinline__ float bce4(const float4& z, const float4& x) {
    return bce_fast(z.x, x.x) + bce_fast(z.y, x.y)
         + bce_fast(z.z, x.z) + bce_fast(z.w, x.w);
}

// ---- Kernel A: streaming S_all + cell pass (pure slot writes) -------------
__global__ __launch_bounds__(BDIM) void mega_a(
    const float* __restrict__ o0, const float* __restrict__ l0,
    const float* __restrict__ o1, const float* __restrict__ l1,
    const float* __restrict__ o2, const float* __restrict__ l2,
    double* __restrict__ slotS, double* __restrict__ slotC,
    float4* __restrict__ pbox, float* __restrict__ noobj)
{
    if (blockIdx.x >= NCELLB) {
        // streaming role: one pass, 4 float4/thread/array, loads batched
        int sb = blockIdx.x - NCELLB;      // 0..1768
        int blk0, n4;
        const float4 *O4, *L4;
        if (sb < 85)       { blk0=0;   n4=86190;   O4=(const float4*)o0; L4=(const float4*)l0; }
        else if (sb < 422) { blk0=85;  n4=344760;  O4=(const float4*)o1; L4=(const float4*)l1; }
        else               { blk0=422; n4=1379040; O4=(const float4*)o2; L4=(const float4*)l2; }

        int rb   = sb - blk0;
        int base = rb * (BDIM * 4) + (int)threadIdx.x;
        float s0 = 0.f, s1 = 0.f, s2 = 0.f, s3 = 0.f;
        if ((rb + 1) * (BDIM * 4) <= n4) {
            float4 a0 = O4[base];          float4 b0 = L4[base];
            float4 a1 = O4[base +   BDIM]; float4 b1 = L4[base +   BDIM];
            float4 a2 = O4[base + 2*BDIM]; float4 b2 = L4[base + 2*BDIM];
            float4 a3 = O4[base + 3*BDIM]; float4 b3 = L4[base + 3*BDIM];
            s0 = bce4(b0, a0); s1 = bce4(b1, a1);
            s2 = bce4(b2, a2); s3 = bce4(b3, a3);
        } else {
            #pragma unroll
            for (int k = 0; k < 4; k++) {
                int j = base + k * BDIM;
                if (j < n4) { float4 a = O4[j], b = L4[j]; s0 += bce4(b, a); }
            }
        }
        float s = (s0 + s1) + (s2 + s3);
        __shared__ float sb4[4];
        #pragma unroll
        for (int off = 32; off > 0; off >>= 1) s += __shfl_down(s, off, 64);
        if ((threadIdx.x & 63) == 0) sb4[threadIdx.x >> 6] = s;
        __syncthreads();
        if (threadIdx.x == 0)
            slotS[sb] = (double)sb4[0] + (double)sb4[1]
                      + (double)sb4[2] + (double)sb4[3];
        return;
    }

    // ---- cell role: ch0..4 losses + pbox/noobj ----------------------------
    int cb = blockIdx.x;                   // 0..333
    int layer, cblk0;
    if (cb < 16)      { layer = 0; cblk0 = 0; }
    else if (cb < 80) { layer = 1; cblk0 = 16; }
    else              { layer = 2; cblk0 = 80; }
    const int g     = (layer == 0) ? 13 : (layer == 1) ? 26 : 52;
    const int Nlimg = g * g * 3;
    const int Cl    = 8 * Nlimg;
    const int cbase = (layer == 0) ? 0 : (layer == 1) ? 4056 : 20280;
    const float* O  = (layer == 0) ? o0 : (layer == 1) ? o1 : o2;
    const float* L  = (layer == 0) ? l0 : (layer == 1) ? l1 : l2;
    const float gf  = (float)g;
    const float inp = gf * 32.f;

    int  cell = (cb - cblk0) * BDIM + (int)threadIdx.x;
    bool live = (cell < Cl);
    float s_sub=0.f, s_xy=0.f, s_wh=0.f, s_conf=0.f, s_obj=0.f, s_s1=0.f;
    if (live) {
        const float* op = O + (size_t)cell * 85;
        const float* lp = L + (size_t)cell * 85;
        float x0=op[0], x1=op[1], x2=op[2], x3=op[3], x4=op[4];
        float lx=lp[0], ly=lp[1], lw=lp[2], lh=lp[3], lobj=lp[4];
        int a  = cell % 3;
        int xi = (cell / 3) % g;
        int yi = (cell / (3 * g)) % g;
        float aw = c_aw[layer][a], ah = c_ah[layer][a];

        float c4 = bce_fast(lobj, x4);
        s_sub  = bce_fast(lx,x0) + bce_fast(ly,x1)
               + bce_fast(lw,x2) + bce_fast(lh,x3) + c4;
        s_conf = c4;
        s_obj  = lobj;
        s_xy   = bce_fast(lx*gf - (float)xi, x0)
               + bce_fast(ly*gf - (float)yi, x1);

        // accurate exp/sigmoid: pbox feeds the 0.5-threshold compare
        float px = (1.f/(1.f+expf(-x0)) + (float)xi) / gf;
        float py = (1.f/(1.f+expf(-x1)) + (float)yi) / gf;
        float pw = expf(x2) * aw / inp;
        float ph = expf(x3) * ah / inp;
        pbox[cbase + cell]  = make_float4(px, py, pw, ph);
        noobj[cbase + cell] = 1.f - lobj;

        if (lobj != 0.f) {
            float bls = 2.f - lw * lh;
            s_s1 = lobj * bls;
            float dw = logf(lw * inp / aw) - x2;
            float dh = logf(lh * inp / ah) - x3;
            s_wh = lobj * bls * 0.5f * (dw * dw + dh * dh);
        }
    }

    __shared__ float sb6[6][4];
    float v[6] = {s_sub, s_xy, s_wh, s_conf, s_obj, s_s1};
    #pragma unroll
    for (int q = 0; q < 6; q++) {
        float x = v[q];
        #pragma unroll
        for (int off = 32; off > 0; off >>= 1) x += __shfl_down(x, off, 64);
        if ((threadIdx.x & 63) == 0) sb6[q][threadIdx.x >> 6] = x;
    }
    __syncthreads();
    if (threadIdx.x < 6) {
        int q = threadIdx.x;
        slotC[cb * 6 + q] = (double)sb6[q][0] + (double)sb6[q][1]
                          + (double)sb6[q][2] + (double)sb6[q][3];
    }
}

// ---- Kernel B: ignore-mask, NO fences/atomics — pure slot write -----------
__global__ __launch_bounds__(BDIM) void ignore_nb(
    const float* __restrict__ l0, const float* __restrict__ l1,
    const float* __restrict__ l2,
    const float4* __restrict__ pbox, const float* __restrict__ noobj,
    double* __restrict__ slotB)
{
    int layer, img, chunk;
    if (blockIdx.x < 16)      { layer = 0; img = blockIdx.x >> 1; chunk = blockIdx.x & 1; }
    else if (blockIdx.x < 80) { int t = blockIdx.x - 16; layer = 1; img = t >> 3; chunk = t & 7; }
    else                      { int t = blockIdx.x - 80; layer = 2; img = t >> 5; chunk = t & 31; }
    const int g     = (layer == 0) ? 13 : (layer == 1) ? 26 : 52;
    const int Nlimg = g * g * 3;
    const int cbase = (layer == 0) ? 0 : (layer == 1) ? 4056 : 20280;
    const float* L  = (layer == 0) ? l0 : (layer == 1) ? l1 : l2;

    int ci = chunk * BDIM + (int)threadIdx.x;
    bool live = (ci < Nlimg);
    int cell = cbase + img * Nlimg + (live ? ci : 0);

    float pminx=0, pmaxx=0, pminy=0, pmaxy=0, a1=0, nb=0;
    if (live) {
        float4 p = pbox[cell];
        pminx = p.x - p.z*0.5f; pmaxx = p.x + p.z*0.5f;
        pminy = p.y - p.w*0.5f; pmaxy = p.y + p.w*0.5f;
        a1 = p.z * p.w;
        nb = noobj[cell];
    }

    // discover targets: noobj==0.0f marks obj!=0 cells (exact: 1-1=0)
    __shared__ int    sIdx[SCAP];
    __shared__ int    sN;
    __shared__ float4 sT[SCAP];
    if (threadIdx.x == 0) sN = 0;
    __syncthreads();
    const float* nob = noobj + cbase + img * Nlimg;
    for (int i = threadIdx.x; i < Nlimg; i += BDIM) {
        if (nob[i] == 0.0f) {
            int p = atomicAdd(&sN, 1);     // LDS atomic (workgroup scope)
            if (p < SCAP) sIdx[p] = i;
        }
    }
    __syncthreads();
    int n = min(sN, SCAP);
    for (int i = threadIdx.x; i < n; i += BDIM) {
        const float* lp = L + (size_t)(img * Nlimg + sIdx[i]) * 85;
        sT[i] = make_float4(lp[0], lp[1], lp[2], lp[3]);
    }
    __syncthreads();

    float best = -1.f;                     // replicates where(valid, iou, -1)
    if (live) {
        for (int j = 0; j < n; j++) {
            float4 t = sT[j];
            float hw = t.z*0.5f, hh = t.w*0.5f;
            // reference uses maximum for BOTH mins and maxes (replicated bug)
            float imnx = fmaxf(pminx, t.x - hw);
            float imxx = fmaxf(pmaxx, t.x + hw);
            float imny = fmaxf(pminy, t.y - hh);
            float imxy = fmaxf(pmaxy, t.y + hh);
            float iw = fmaxf(imxx - imnx, 0.f);
            float ih = fmaxf(imxy - imny, 0.f);
            float inter = iw * ih;
            float iou = inter / (a1 + t.z*t.w - inter);
            best = fmaxf(best, iou);
            if (best >= 0.5f) break;       // max: exact & order-independent
        }
    }

    float v = (live && best < 0.5f) ? nb : 0.f;
    __shared__ float sbr[4];
    #pragma unroll
    for (int off = 32; off > 0; off >>= 1) v += __shfl_down(v, off, 64);
    if ((threadIdx.x & 63) == 0) sbr[threadIdx.x >> 6] = v;
    __syncthreads();
    if (threadIdx.x == 0)
        slotB[blockIdx.x] = (double)sbr[0] + (double)sbr[1]
                          + (double)sbr[2] + (double)sbr[3];
}

// ---- Kernel C: 1-block finalize (coherence via kernel boundary) -----------
__global__ __launch_bounds__(BDIM) void finalize_k(
    const double* __restrict__ slotS, const double* __restrict__ slotC,
    const double* __restrict__ slotB, float* __restrict__ out)
{
    double vals[24];                       // [l*8]: S_all, sub,xy,wh,conf,obj,s1,ni
    #pragma unroll
    for (int k = 0; k < 24; k++) vals[k] = 0.0;

    for (int i = threadIdx.x; i < NSTREAMB; i += BDIM) {
        double x = slotS[i];
        int l = (i < 85) ? 0 : (i < 422) ? 1 : 2;
        vals[l * 8] += x;
    }
    for (int i = threadIdx.x; i < NCELLB * 6; i += BDIM) {
        double x = slotC[i];
        int q  = i % 6;
        int cb = i / 6;
        int l = (cb < 16) ? 0 : (cb < 80) ? 1 : 2;
        vals[l * 8 + 1 + q] += x;
    }
    for (int i = threadIdx.x; i < NB_IGNORE; i += BDIM) {
        double x = slotB[i];
        int l = (i < 16) ? 0 : (i < 80) ? 1 : 2;
        vals[l * 8 + 7] += x;
    }

    __shared__ double dsum[24][4];
    {
        int lane = threadIdx.x & 63, wid = threadIdx.x >> 6;
        #pragma unroll
        for (int k = 0; k < 24; k++) {
            double r = vals[k];
            #pragma unroll
            for (int off = 32; off > 0; off >>= 1) r += __shfl_down(r, off, 64);
            if (lane == 0) dsum[k][wid] = r;
        }
    }
    __syncthreads();
    if (threadIdx.x == 0) {
        double loss = 0.0;
        const int gsz[3] = {13, 26, 52};
        for (int l = 0; l < 3; l++) {
            double C = 8.0 * gsz[l] * gsz[l] * 3.0;
            double V[8];
            #pragma unroll
            for (int k = 0; k < 8; k++)
                V[k] = dsum[l*8+k][0] + dsum[l*8+k][1]
                     + dsum[l*8+k][2] + dsum[l*8+k][3];
            // V: 0 S_all, 1 sub, 2 xy, 3 wh, 4 conf, 5 obj, 6 s1, 7 ni
            double cls = (V[0] - V[1]) / (C * 80.0);
            loss += ( (V[2]/(C*2.0))*V[6] + V[3]
                    + (V[4]/C)*(V[5]+V[7]) + cls*V[5] ) / 8.0;
        }
        out[0] = (float)loss;
    }
}

extern "C" void kernel_launch(void* const* d_in, const int* in_sizes, int n_in,
                              void* d_out, int out_size, void* d_ws, size_t ws_size,
                              hipStream_t stream)
{
    const float* o0 = (const float*)d_in[0];
    const float* l0 = (const float*)d_in[1];
    const float* o1 = (const float*)d_in[2];
    const float* l1 = (const float*)d_in[3];
    const float* o2 = (const float*)d_in[4];
    const float* l2 = (const float*)d_in[5];

    double* slotS = (double*)((char*)d_ws + 64);
    double* slotC = (double*)((char*)d_ws + 14336);
    double* slotB = (double*)((char*)d_ws + 30720);
    float4* pbox  = (float4*)((char*)d_ws + 33792);
    float*  noobj = (float*)((char*)d_ws + 1396608);

    mega_a<<<NBLK_A, BDIM, 0, stream>>>(o0, l0, o1, l1, o2, l2,
                                        slotS, slotC, pbox, noobj);
    ignore_nb<<<NB_IGNORE, BDIM, 0, stream>>>(l0, l1, l2, pbox, noobj, slotB);
    finalize_k<<<1, BDIM, 0, stream>>>(slotS, slotC, slotB, (float*)d_out);
}

// Round 9
// 155.554 us; speedup vs baseline: 2.8327x; 1.0307x over previous
//
#include <hip/hip_runtime.h>
#include <math.h>

#define BDIM 256
#define NCELLB 334             // cell blocks
#define NSTREAMB 1769          // single-pass streaming blocks
#define NBLK_A (NCELLB + NSTREAMB)   // 2103
#define NB_IGNORE 336          // 16 + 64 + 256 (image, chunk)
#define SCAP 1024              // target capacity per image (mean ~162)

// Anchors per layer: l0 = mask[6,7,8], l1 = [3,4,5], l2 = [0,1,2]
__device__ __constant__ float c_aw[3][3] = {{116.f,156.f,373.f},{30.f,62.f,59.f},{10.f,16.f,33.f}};
__device__ __constant__ float c_ah[3][3] = {{90.f,198.f,326.f},{61.f,45.f,119.f},{13.f,30.f,23.f}};

// ws layout — no zeroing, no global atomics, no fences anywhere:
//   slotS @64      1769 dbl  per-streaming-block S_all partial (unconditional)
//   slotC @14336   334*6 dbl per-cell-block partials (sub,xy,wh,conf,obj,s1)
//   slotB @30720   336 dbl   per-ignore-block ni partial (unconditional)
//   pbox  @33792   85176 f4  decoded pred boxes
//   noobj @1396608 85176 f   1-obj (0.0 marks target cell — exact)
// Coherence across kernels: stream ordering at dispatch boundaries only.
// Layer cell bases {0,4056,20280}; streaming-block bases {0,85,422}.

__device__ __forceinline__ float bce_fast(float z, float x) {
    float t = __expf(-fabsf(x));
    return fmaxf(x, 0.f) - x * z + __logf(1.f + t);
}
__device__ __forceinline__ float bce4(const float4& z, const float4& x) {
    return bce_fast(z.x, x.x) + bce_fast(z.y, x.y)
         + bce_fast(z.z, x.z) + bce_fast(z.w, x.w);
}

// ---- Kernel A: streaming S_all + cell pass (pure slot writes) -------------
__global__ __launch_bounds__(BDIM) void mega_a(
    const float* __restrict__ o0, const float* __restrict__ l0,
    const float* __restrict__ o1, const float* __restrict__ l1,
    const float* __restrict__ o2, const float* __restrict__ l2,
    double* __restrict__ slotS, double* __restrict__ slotC,
    float4* __restrict__ pbox, float* __restrict__ noobj)
{
    if (blockIdx.x >= NCELLB) {
        // streaming role: one pass, 4 float4/thread/array, loads batched
        int sb = blockIdx.x - NCELLB;      // 0..1768
        int blk0, n4;
        const float4 *O4, *L4;
        if (sb < 85)       { blk0=0;   n4=86190;   O4=(const float4*)o0; L4=(const float4*)l0; }
        else if (sb < 422) { blk0=85;  n4=344760;  O4=(const float4*)o1; L4=(const float4*)l1; }
        else               { blk0=422; n4=1379040; O4=(const float4*)o2; L4=(const float4*)l2; }

        int rb   = sb - blk0;
        int base = rb * (BDIM * 4) + (int)threadIdx.x;
        float s0 = 0.f, s1 = 0.f, s2 = 0.f, s3 = 0.f;
        if ((rb + 1) * (BDIM * 4) <= n4) {
            float4 a0 = O4[base];          float4 b0 = L4[base];
            float4 a1 = O4[base +   BDIM]; float4 b1 = L4[base +   BDIM];
            float4 a2 = O4[base + 2*BDIM]; float4 b2 = L4[base + 2*BDIM];
            float4 a3 = O4[base + 3*BDIM]; float4 b3 = L4[base + 3*BDIM];
            s0 = bce4(b0, a0); s1 = bce4(b1, a1);
            s2 = bce4(b2, a2); s3 = bce4(b3, a3);
        } else {
            #pragma unroll
            for (int k = 0; k < 4; k++) {
                int j = base + k * BDIM;
                if (j < n4) { float4 a = O4[j], b = L4[j]; s0 += bce4(b, a); }
            }
        }
        float s = (s0 + s1) + (s2 + s3);
        __shared__ float sb4[4];
        #pragma unroll
        for (int off = 32; off > 0; off >>= 1) s += __shfl_down(s, off, 64);
        if ((threadIdx.x & 63) == 0) sb4[threadIdx.x >> 6] = s;
        __syncthreads();
        if (threadIdx.x == 0)
            slotS[sb] = (double)sb4[0] + (double)sb4[1]
                      + (double)sb4[2] + (double)sb4[3];
        return;
    }

    // ---- cell role: ch0..4 losses + pbox/noobj ----------------------------
    int cb = blockIdx.x;                   // 0..333
    int layer, cblk0;
    if (cb < 16)      { layer = 0; cblk0 = 0; }
    else if (cb < 80) { layer = 1; cblk0 = 16; }
    else              { layer = 2; cblk0 = 80; }
    const int g     = (layer == 0) ? 13 : (layer == 1) ? 26 : 52;
    const int Nlimg = g * g * 3;
    const int Cl    = 8 * Nlimg;
    const int cbase = (layer == 0) ? 0 : (layer == 1) ? 4056 : 20280;
    const float* O  = (layer == 0) ? o0 : (layer == 1) ? o1 : o2;
    const float* L  = (layer == 0) ? l0 : (layer == 1) ? l1 : l2;
    const float gf  = (float)g;
    const float inp = gf * 32.f;

    int  cell = (cb - cblk0) * BDIM + (int)threadIdx.x;
    bool live = (cell < Cl);
    float s_sub=0.f, s_xy=0.f, s_wh=0.f, s_conf=0.f, s_obj=0.f, s_s1=0.f;
    if (live) {
        const float* op = O + (size_t)cell * 85;
        const float* lp = L + (size_t)cell * 85;
        float x0=op[0], x1=op[1], x2=op[2], x3=op[3], x4=op[4];
        float lx=lp[0], ly=lp[1], lw=lp[2], lh=lp[3], lobj=lp[4];
        int a  = cell % 3;
        int xi = (cell / 3) % g;
        int yi = (cell / (3 * g)) % g;
        float aw = c_aw[layer][a], ah = c_ah[layer][a];

        float c4 = bce_fast(lobj, x4);
        s_sub  = bce_fast(lx,x0) + bce_fast(ly,x1)
               + bce_fast(lw,x2) + bce_fast(lh,x3) + c4;
        s_conf = c4;
        s_obj  = lobj;
        s_xy   = bce_fast(lx*gf - (float)xi, x0)
               + bce_fast(ly*gf - (float)yi, x1);

        // accurate exp/sigmoid: pbox feeds the 0.5-threshold compare
        float px = (1.f/(1.f+expf(-x0)) + (float)xi) / gf;
        float py = (1.f/(1.f+expf(-x1)) + (float)yi) / gf;
        float pw = expf(x2) * aw / inp;
        float ph = expf(x3) * ah / inp;
        pbox[cbase + cell]  = make_float4(px, py, pw, ph);
        noobj[cbase + cell] = 1.f - lobj;

        if (lobj != 0.f) {
            float bls = 2.f - lw * lh;
            s_s1 = lobj * bls;
            float dw = logf(lw * inp / aw) - x2;
            float dh = logf(lh * inp / ah) - x3;
            s_wh = lobj * bls * 0.5f * (dw * dw + dh * dh);
        }
    }

    __shared__ float sb6[6][4];
    float v[6] = {s_sub, s_xy, s_wh, s_conf, s_obj, s_s1};
    #pragma unroll
    for (int q = 0; q < 6; q++) {
        float x = v[q];
        #pragma unroll
        for (int off = 32; off > 0; off >>= 1) x += __shfl_down(x, off, 64);
        if ((threadIdx.x & 63) == 0) sb6[q][threadIdx.x >> 6] = x;
    }
    __syncthreads();
    if (threadIdx.x < 6) {
        int q = threadIdx.x;
        slotC[cb * 6 + q] = (double)sb6[q][0] + (double)sb6[q][1]
                          + (double)sb6[q][2] + (double)sb6[q][3];
    }
}

// ---- Kernel B: ignore-mask with BATCHED discovery scan (1 round-trip) -----
__global__ __launch_bounds__(BDIM) void ignore_nb(
    const float* __restrict__ l0, const float* __restrict__ l1,
    const float* __restrict__ l2,
    const float4* __restrict__ pbox, const float* __restrict__ noobj,
    double* __restrict__ slotB)
{
    int layer, img, chunk;
    if (blockIdx.x < 16)      { layer = 0; img = blockIdx.x >> 1; chunk = blockIdx.x & 1; }
    else if (blockIdx.x < 80) { int t = blockIdx.x - 16; layer = 1; img = t >> 3; chunk = t & 7; }
    else                      { int t = blockIdx.x - 80; layer = 2; img = t >> 5; chunk = t & 31; }
    const int g     = (layer == 0) ? 13 : (layer == 1) ? 26 : 52;
    const int Nlimg = g * g * 3;
    const int cbase = (layer == 0) ? 0 : (layer == 1) ? 4056 : 20280;
    const float* L  = (layer == 0) ? l0 : (layer == 1) ? l1 : l2;

    int ci = chunk * BDIM + (int)threadIdx.x;
    bool live = (ci < Nlimg);
    int cell = cbase + img * Nlimg + (live ? ci : 0);

    float pminx=0, pmaxx=0, pminy=0, pmaxy=0, a1=0, nb=0;
    if (live) {
        float4 p = pbox[cell];
        pminx = p.x - p.z*0.5f; pmaxx = p.x + p.z*0.5f;
        pminy = p.y - p.w*0.5f; pmaxy = p.y + p.w*0.5f;
        a1 = p.z * p.w;
        nb = noobj[cell];
    }

    // ---- discover targets: batched register load of the whole strip -------
    // noobj==0.0f marks obj!=0 cells (exact: 1-1=0). All loads issued before
    // any processing -> 1 memory round-trip instead of Nlimg/BDIM serialized.
    __shared__ int    sIdx[SCAP];
    __shared__ int    sN;
    __shared__ float4 sT[SCAP];
    if (threadIdx.x == 0) sN = 0;

    const float*  nobS = noobj + cbase + img * Nlimg;
    const float4* nob4 = (const float4*)nobS;
    const int Nf4 = Nlimg >> 2;            // 126 / 507 / 2028
    const int K   = (Nf4 + BDIM - 1) / BDIM;   // 1 / 2 / 8
    float4 vv[8];
    bool   vld[8];
    #pragma unroll
    for (int k = 0; k < 8; k++) {
        vld[k] = false;
        if (k < K) {
            int i = (int)threadIdx.x + k * BDIM;
            if (i < Nf4) { vv[k] = nob4[i]; vld[k] = true; }
        }
    }
    // tail floats (Nlimg & 3 == 3 for layer 0, else 0)
    int   tn = Nlimg & 3;
    bool  tl = ((int)threadIdx.x < tn);
    float tv = 0.f;
    if (tl) tv = nobS[Nf4 * 4 + (int)threadIdx.x];
    __syncthreads();                       // sN=0 visible

    #pragma unroll
    for (int k = 0; k < 8; k++) {
        if (vld[k]) {
            int i4 = ((int)threadIdx.x + k * BDIM) * 4;
            if (vv[k].x == 0.0f) { int p = atomicAdd(&sN, 1); if (p < SCAP) sIdx[p] = i4 + 0; }
            if (vv[k].y == 0.0f) { int p = atomicAdd(&sN, 1); if (p < SCAP) sIdx[p] = i4 + 1; }
            if (vv[k].z == 0.0f) { int p = atomicAdd(&sN, 1); if (p < SCAP) sIdx[p] = i4 + 2; }
            if (vv[k].w == 0.0f) { int p = atomicAdd(&sN, 1); if (p < SCAP) sIdx[p] = i4 + 3; }
        }
    }
    if (tl && tv == 0.0f) {
        int p = atomicAdd(&sN, 1);
        if (p < SCAP) sIdx[p] = Nf4 * 4 + (int)threadIdx.x;
    }
    __syncthreads();
    int n = min(sN, SCAP);
    for (int i = threadIdx.x; i < n; i += BDIM) {
        const float* lp = L + (size_t)(img * Nlimg + sIdx[i]) * 85;
        sT[i] = make_float4(lp[0], lp[1], lp[2], lp[3]);
    }
    __syncthreads();

    float best = -1.f;                     // replicates where(valid, iou, -1)
    if (live) {
        for (int j = 0; j < n; j++) {
            float4 t = sT[j];
            float hw = t.z*0.5f, hh = t.w*0.5f;
            // reference uses maximum for BOTH mins and maxes (replicated bug)
            float imnx = fmaxf(pminx, t.x - hw);
            float imxx = fmaxf(pmaxx, t.x + hw);
            float imny = fmaxf(pminy, t.y - hh);
            float imxy = fmaxf(pmaxy, t.y + hh);
            float iw = fmaxf(imxx - imnx, 0.f);
            float ih = fmaxf(imxy - imny, 0.f);
            float inter = iw * ih;
            float iou = inter / (a1 + t.z*t.w - inter);
            best = fmaxf(best, iou);
            if (best >= 0.5f) break;       // max: exact & order-independent
        }
    }

    float v = (live && best < 0.5f) ? nb : 0.f;
    __shared__ float sbr[4];
    #pragma unroll
    for (int off = 32; off > 0; off >>= 1) v += __shfl_down(v, off, 64);
    if ((threadIdx.x & 63) == 0) sbr[threadIdx.x >> 6] = v;
    __syncthreads();
    if (threadIdx.x == 0)
        slotB[blockIdx.x] = (double)sbr[0] + (double)sbr[1]
                          + (double)sbr[2] + (double)sbr[3];
}

// ---- Kernel C: 1-block finalize (coherence via kernel boundary) -----------
__global__ __launch_bounds__(BDIM) void finalize_k(
    const double* __restrict__ slotS, const double* __restrict__ slotC,
    const double* __restrict__ slotB, float* __restrict__ out)
{
    double vals[24];                       // [l*8]: S_all, sub,xy,wh,conf,obj,s1,ni
    #pragma unroll
    for (int k = 0; k < 24; k++) vals[k] = 0.0;

    for (int i = threadIdx.x; i < NSTREAMB; i += BDIM) {
        double x = slotS[i];
        int l = (i < 85) ? 0 : (i < 422) ? 1 : 2;
        vals[l * 8] += x;
    }
    for (int i = threadIdx.x; i < NCELLB * 6; i += BDIM) {
        double x = slotC[i];
        int q  = i % 6;
        int cb = i / 6;
        int l = (cb < 16) ? 0 : (cb < 80) ? 1 : 2;
        vals[l * 8 + 1 + q] += x;
    }
    for (int i = threadIdx.x; i < NB_IGNORE; i += BDIM) {
        double x = slotB[i];
        int l = (i < 16) ? 0 : (i < 80) ? 1 : 2;
        vals[l * 8 + 7] += x;
    }

    __shared__ double dsum[24][4];
    {
        int lane = threadIdx.x & 63, wid = threadIdx.x >> 6;
        #pragma unroll
        for (int k = 0; k < 24; k++) {
            double r = vals[k];
            #pragma unroll
            for (int off = 32; off > 0; off >>= 1) r += __shfl_down(r, off, 64);
            if (lane == 0) dsum[k][wid] = r;
        }
    }
    __syncthreads();
    if (threadIdx.x == 0) {
        double loss = 0.0;
        const int gsz[3] = {13, 26, 52};
        for (int l = 0; l < 3; l++) {
            double C = 8.0 * gsz[l] * gsz[l] * 3.0;
            double V[8];
            #pragma unroll
            for (int k = 0; k < 8; k++)
                V[k] = dsum[l*8+k][0] + dsum[l*8+k][1]
                     + dsum[l*8+k][2] + dsum[l*8+k][3];
            // V: 0 S_all, 1 sub, 2 xy, 3 wh, 4 conf, 5 obj, 6 s1, 7 ni
            double cls = (V[0] - V[1]) / (C * 80.0);
            loss += ( (V[2]/(C*2.0))*V[6] + V[3]
                    + (V[4]/C)*(V[5]+V[7]) + cls*V[5] ) / 8.0;
        }
        out[0] = (float)loss;
    }
}

extern "C" void kernel_launch(void* const* d_in, const int* in_sizes, int n_in,
                              void* d_out, int out_size, void* d_ws, size_t ws_size,
                              hipStream_t stream)
{
    const float* o0 = (const float*)d_in[0];
    const float* l0 = (const float*)d_in[1];
    const float* o1 = (const float*)d_in[2];
    const float* l1 = (const float*)d_in[3];
    const float* o2 = (const float*)d_in[4];
    const float* l2 = (const float*)d_in[5];

    double* slotS = (double*)((char*)d_ws + 64);
    double* slotC = (double*)((char*)d_ws + 14336);
    double* slotB = (double*)((char*)d_ws + 30720);
    float4* pbox  = (float4*)((char*)d_ws + 33792);
    float*  noobj = (float*)((char*)d_ws + 1396608);

    mega_a<<<NBLK_A, BDIM, 0, stream>>>(o0, l0, o1, l1, o2, l2,
                                        slotS, slotC, pbox, noobj);
    ignore_nb<<<NB_IGNORE, BDIM, 0, stream>>>(l0, l1, l2, pbox, noobj, slotB);
    finalize_k<<<1, BDIM, 0, stream>>>(slotS, slotC, slotB, (float*)d_out);
}